// Round 9
// baseline (559.088 us; speedup 1.0000x reference)
//
#include <hip/hip_runtime.h>
#include <hip/hip_bf16.h>
#include <stdint.h>

#define DIMN 2048
#define KVD  512
#define NH   32
#define BATCH 2
#define SEQ  2048
#define ROWS (BATCH*SEQ)   // 4096
#define NT   (SEQ/64)      // 32 k/q tiles of 64

typedef __attribute__((ext_vector_type(4))) float f32x4;
typedef __attribute__((ext_vector_type(8))) short bf16x8;

__device__ __forceinline__ float bf2f(short s){
  union{uint32_t u;float f;} v; v.u=((uint32_t)(uint16_t)s)<<16; return v.f;
}
__device__ __forceinline__ short f2bf_rn(float f){
  __hip_bfloat16 h = __float2bfloat16(f);   // hardware RNE convert
  short s; __builtin_memcpy(&s, &h, 2); return s;
}
__device__ __forceinline__ f32x4 mfma16(bf16x8 a, bf16x8 b, f32x4 c){
  return __builtin_amdgcn_mfma_f32_16x16x32_bf16(a,b,c,0,0,0);
}
__device__ __forceinline__ short ternbf(float v, float thr){
  return v > thr ? (short)0x3F80 : (v < -thr ? (short)0xBF80 : (short)0);
}
// native exp2 (single v_exp_f32) — exp2f() is the precise ocml call, ~10x costlier
__device__ __forceinline__ float exp2_fast(float x){
#if __has_builtin(__builtin_amdgcn_exp2f)
  return __builtin_amdgcn_exp2f(x);
#else
  return __expf(x * 0.69314718056f);
#endif
}
// async global->LDS, 16B per lane; LDS dest = wave-uniform base + lane*16
__device__ __forceinline__ void gload16(const short* g, short* l){
  __builtin_amdgcn_global_load_lds(
      (const __attribute__((address_space(1))) uint32_t*)g,
      (__attribute__((address_space(3))) uint32_t*)l, 16, 0, 0);
}

// ---------------- abs-mean reduction (deterministic, two stage) ----------------
__global__ void k_abssum4(const float* __restrict__ w0, const float* __restrict__ w1,
                          const float* __restrict__ w2, const float* __restrict__ w3,
                          float* __restrict__ partial){
  __shared__ float red[256];
  const float* ptrs[4] = {w0, w1, w2, w3};
  const int ns[4] = {DIMN*DIMN, KVD*DIMN, KVD*DIMN, DIMN*DIMN};
  const int wi = blockIdx.y;
  const float* w = ptrs[wi];
  const int n = ns[wi];
  float s = 0.f;
  for (int i = blockIdx.x*256 + threadIdx.x; i < n; i += 256*gridDim.x) s += fabsf(w[i]);
  red[threadIdx.x] = s; __syncthreads();
  for (int o = 128; o > 0; o >>= 1){
    if (threadIdx.x < o) red[threadIdx.x] += red[threadIdx.x+o];
    __syncthreads();
  }
  if (threadIdx.x == 0) partial[wi*256 + blockIdx.x] = red[0];
}

__global__ void k_scales(const float* __restrict__ partial, float* __restrict__ scales){
  __shared__ float red[256];
  int t = threadIdx.x;
  const int counts[4] = {DIMN*DIMN, KVD*DIMN, KVD*DIMN, DIMN*DIMN};
  for (int wi = 0; wi < 4; wi++){
    red[t] = partial[wi*256 + t]; __syncthreads();
    for (int o = 128; o > 0; o >>= 1){
      if (t < o) red[t] += red[t+o];
      __syncthreads();
    }
    if (t == 0){
      float mean = red[0] / (float)counts[wi];
      scales[wi] = 0.05f * fmaxf(mean, 1e-6f);
    }
    __syncthreads();
  }
}

// ---------------- pre-pass: x -> hi/lo bf16 ----------------
__global__ void k_prep_x(const float* __restrict__ x, short* __restrict__ hi,
                         short* __restrict__ lo){
  long i = ((long)blockIdx.x*256 + threadIdx.x)*8;
  f32x4 a = *(const f32x4*)(x+i);
  f32x4 b = *(const f32x4*)(x+i+4);
  bf16x8 h, l;
  #pragma unroll
  for (int j = 0; j < 4; j++){
    short p = f2bf_rn(a[j]); h[j]   = p; l[j]   = f2bf_rn(a[j]-bf2f(p));
    short q = f2bf_rn(b[j]); h[4+j] = q; l[4+j] = f2bf_rn(b[j]-bf2f(q));
  }
  *(bf16x8*)(hi+i) = h;
  *(bf16x8*)(lo+i) = l;
}

// ---------------- pre-pass: ternarize all 4 weights -> bf16 ----------------
__global__ void k_tern4(const float* __restrict__ w0, const float* __restrict__ w1,
                        const float* __restrict__ w2, const float* __restrict__ w3,
                        short* __restrict__ o0, short* __restrict__ o1,
                        short* __restrict__ o2, short* __restrict__ o3,
                        const float* __restrict__ scales){
  const float* ws[4] = {w0, w1, w2, w3};
  short* os[4] = {o0, o1, o2, o3};
  const int ns[4] = {DIMN*DIMN, KVD*DIMN, KVD*DIMN, DIMN*DIMN};
  const int wi = blockIdx.y;
  long i = ((long)blockIdx.x*256 + threadIdx.x)*8;
  if (i >= ns[wi]) return;
  const float thr = scales[wi];
  const float* w = ws[wi];
  f32x4 a = *(const f32x4*)(w+i);
  f32x4 b = *(const f32x4*)(w+i+4);
  bf16x8 t;
  #pragma unroll
  for (int j = 0; j < 4; j++){
    t[j]   = ternbf(a[j], thr);
    t[4+j] = ternbf(b[j], thr);
  }
  *(bf16x8*)(os[wi]+i) = t;
}

// ------- GEMM core: m97 structure (global_load_lds, linear [128][64] LDS, BK=64) -------
// SPLITA: A=Ahg+Xlg (hi/lo).  SPLITB: B=Bg+Xlg (hi/lo).  OUTF32: f32 output.
template<int SPLITA, int SPLITB, int OUTF32>
__device__ __forceinline__ void gemm_core(
    const short* __restrict__ Ahg, const short* __restrict__ Xlg,
    const short* __restrict__ Bg,
    float* __restrict__ Of, short* __restrict__ Oh, short* __restrict__ Ol,
    bool writelo, int N, int K, int bn, int bm,
    short (*AhS)[64], short (*XlS)[64], short (*BsS)[64]){
  const int tid = threadIdx.x, lane = tid & 63, w = tid >> 6;
  const int wr = w >> 1, wc = w & 1;
  const int la = lane & 15, kg = lane >> 4;
  const int xrb = SPLITA ? bm : bn;   // rows staged into XlS
  f32x4 acc[4][4] = {};
  for (int k0 = 0; k0 < K; k0 += 64){
    #pragma unroll
    for (int j = 0; j < 4; j++){
      const int flat = (w*4 + j)*64 + lane;          // 16B chunk id (lane-varying)
      const int row = flat >> 3, c16 = (flat & 7)*8;
      short* lb = &AhS[0][0] + (w*4 + j)*512;        // wave-uniform LDS base (1KB)
      gload16(Ahg + (long)(bm+row)*K + k0 + c16, lb);
    }
    if constexpr (SPLITA || SPLITB){
      #pragma unroll
      for (int j = 0; j < 4; j++){
        const int flat = (w*4 + j)*64 + lane;
        const int row = flat >> 3, c16 = (flat & 7)*8;
        short* lb = &XlS[0][0] + (w*4 + j)*512;
        gload16(Xlg + (long)(xrb+row)*K + k0 + c16, lb);
      }
    }
    #pragma unroll
    for (int j = 0; j < 4; j++){
      const int flat = (w*4 + j)*64 + lane;
      const int row = flat >> 3, c16 = (flat & 7)*8;
      short* lb = &BsS[0][0] + (w*4 + j)*512;
      gload16(Bg + (long)(bn+row)*K + k0 + c16, lb);
    }
    __syncthreads();   // compiler drains vmcnt before s_barrier
    #pragma unroll
    for (int ks = 0; ks < 2; ks++){
      bf16x8 af[4], bfr[4];
      #pragma unroll
      for (int mi = 0; mi < 4; mi++)
        af[mi] = *(bf16x8*)&AhS[wr*64 + mi*16 + la][ks*32 + kg*8];
      #pragma unroll
      for (int ni = 0; ni < 4; ni++)
        bfr[ni] = *(bf16x8*)&BsS[wc*64 + ni*16 + la][ks*32 + kg*8];
      #pragma unroll
      for (int mi = 0; mi < 4; mi++)
        #pragma unroll
        for (int ni = 0; ni < 4; ni++)
          acc[mi][ni] = mfma16(af[mi], bfr[ni], acc[mi][ni]);
      if constexpr (SPLITA){
        bf16x8 alf[4];
        #pragma unroll
        for (int mi = 0; mi < 4; mi++)
          alf[mi] = *(bf16x8*)&XlS[wr*64 + mi*16 + la][ks*32 + kg*8];
        #pragma unroll
        for (int mi = 0; mi < 4; mi++)
          #pragma unroll
          for (int ni = 0; ni < 4; ni++)
            acc[mi][ni] = mfma16(alf[mi], bfr[ni], acc[mi][ni]);
      }
      if constexpr (SPLITB){
        bf16x8 blf[4];
        #pragma unroll
        for (int ni = 0; ni < 4; ni++)
          blf[ni] = *(bf16x8*)&XlS[wc*64 + ni*16 + la][ks*32 + kg*8];
        #pragma unroll
        for (int mi = 0; mi < 4; mi++)
          #pragma unroll
          for (int ni = 0; ni < 4; ni++)
            acc[mi][ni] = mfma16(af[mi], blf[ni], acc[mi][ni]);
      }
    }
    __syncthreads();
  }
  #pragma unroll
  for (int mi = 0; mi < 4; mi++)
    #pragma unroll
    for (int ni = 0; ni < 4; ni++)
      #pragma unroll
      for (int rr = 0; rr < 4; rr++){
        long row = bm + wr*64 + mi*16 + kg*4 + rr;
        long col = bn + wc*64 + ni*16 + la;
        float v = acc[mi][ni][rr];
        if constexpr (OUTF32){
          Of[row*(long)N + col] = v;
        } else {
          short hb = f2bf_rn(v);
          Oh[row*(long)N + col] = hb;
          if (writelo)
            Ol[row*(long)N + col] = f2bf_rn(v - bf2f(hb));
        }
      }
}

// Merged Q + K + V^T GEMMs: grid (16, 32, 3).
// z=0: Q (x=0..15)  z=1: K (x<4)  z=2: V^T (x<4, A/B roles swapped)
__global__ __launch_bounds__(256) void k_gemm_qkvt(
    const short* __restrict__ xhi, const short* __restrict__ xlo,
    const short* __restrict__ wqT, const short* __restrict__ wkT,
    const short* __restrict__ wvT,
    short* __restrict__ Qh, short* __restrict__ Ql,
    short* __restrict__ KOh, short* __restrict__ KOl, short* __restrict__ VT){
  __shared__ short S0[128][64];
  __shared__ short S1[128][64];
  __shared__ short S2[128][64];
  const int z = blockIdx.z;
  if (z == 0){
    gemm_core<1,0,0>(xhi, xlo, wqT, nullptr, Qh, Ql, true, DIMN, DIMN,
                     blockIdx.x*128, blockIdx.y*128, S0, S1, S2);
  } else if (z == 1){
    if (blockIdx.x >= KVD/128) return;
    gemm_core<1,0,0>(xhi, xlo, wkT, nullptr, KOh, KOl, true, KVD, DIMN,
                     blockIdx.x*128, blockIdx.y*128, S0, S1, S2);
  } else {
    if (blockIdx.x >= KVD/128) return;
    gemm_core<0,1,0>(wvT, xlo, xhi, nullptr, VT, nullptr, false, ROWS, DIMN,
                     blockIdx.y*128, blockIdx.x*128, S0, S1, S2);
  }
}

__global__ __launch_bounds__(256) void k_gemm_o(
    const short* __restrict__ Ahg, const short* __restrict__ Bg,
    float* __restrict__ Of, int N, int K){
  __shared__ short S0[128][64];
  __shared__ short S2[128][64];
  gemm_core<0,0,1>(Ahg, nullptr, Bg, Of, nullptr, nullptr, false, N, K,
                   blockIdx.x*128, blockIdx.y*128, S0, nullptr, S2);
}

// ---------------- GQA causal flash attention ----------------
// Balanced pairing: grid (NT/2=16, head=32, batch=2); block qp does q-tiles {qp, NT-1-qp}
// = exactly 33 k-tiles (uniform). 4 waves x 16 q-rows. K/V^T staged in LDS, pad 68
// (row stride 34 dw -> 0 measured conflicts, r8). Softmax in exp2 domain with native
// v_exp_f32; unconditional online rescale. 3-MFMA hi/lo split scores.
__global__ __launch_bounds__(256) void k_attn(
    const short* __restrict__ qhi, const short* __restrict__ qlo,
    const short* __restrict__ khi, const short* __restrict__ klo,
    const short* __restrict__ vT, short* __restrict__ attout){
  __shared__ short Kh[64][68];
  __shared__ short Kl[64][68];
  __shared__ short Vt[64][68];
  __shared__ short P[64][68];
  const float SC = 0.125f * 1.44269504f;   // log2(e)/sqrt(64)
  const int qp = blockIdx.x, h = blockIdx.y, b = blockIdx.z;
  const int g = h >> 2;
  const int tid = threadIdx.x, w = tid >> 6, lane = tid & 63;
  const int la = lane & 15, kg = lane >> 4;
  const int trow = tid >> 2, tcol = (tid & 3) * 16;   // staging coords

  for (int phase = 0; phase < 2; phase++){
    const int qt = phase ? (NT - 1 - qp) : qp;
    const int qbase = qt*64;

    bf16x8 qh[2], ql[2];
    {
      long qrow = (long)(b*SEQ + qbase + w*16 + la);
      #pragma unroll
      for (int ks = 0; ks < 2; ks++){
        long off = qrow*DIMN + h*64 + ks*32 + kg*8;
        qh[ks] = *(const bf16x8*)(qhi + off);
        ql[ks] = *(const bf16x8*)(qlo + off);
      }
    }
    f32x4 Oacc[4] = {};
    float m[4], l[4];
    #pragma unroll
    for (int r = 0; r < 4; r++){ m[r] = -INFINITY; l[r] = 0.f; }

    for (int kt = 0; kt <= qt; kt++){
      // ---- cooperative stage: K-hi, K-lo (row=token), V^T (row=d) ----
      __syncthreads();
      {
        const short* ksrc  = khi + (long)(b*SEQ + kt*64 + trow)*KVD + g*64 + tcol;
        const short* klsrc = klo + (long)(b*SEQ + kt*64 + trow)*KVD + g*64 + tcol;
        const short* vsrc  = vT  + (long)(g*64 + trow)*ROWS + b*SEQ + kt*64 + tcol;
        *(bf16x8*)&Kh[trow][tcol]   = *(const bf16x8*)ksrc;
        *(bf16x8*)&Kh[trow][tcol+8] = *(const bf16x8*)(ksrc + 8);
        *(bf16x8*)&Kl[trow][tcol]   = *(const bf16x8*)klsrc;
        *(bf16x8*)&Kl[trow][tcol+8] = *(const bf16x8*)(klsrc + 8);
        *(bf16x8*)&Vt[trow][tcol]   = *(const bf16x8*)vsrc;
        *(bf16x8*)&Vt[trow][tcol+8] = *(const bf16x8*)(vsrc + 8);
      }
      __syncthreads();

      // ---- scores (3-MFMA split) ----
      f32x4 s[4];
      __builtin_amdgcn_s_setprio(1);
      #pragma unroll
      for (int ni = 0; ni < 4; ni++){
        f32x4 a = {0.f,0.f,0.f,0.f};
        #pragma unroll
        for (int ks = 0; ks < 2; ks++){
          bf16x8 kh = *(bf16x8*)&Kh[ni*16 + la][ks*32 + kg*8];
          bf16x8 kl = *(bf16x8*)&Kl[ni*16 + la][ks*32 + kg*8];
          a = mfma16(qh[ks], kh, a);
          a = mfma16(ql[ks], kh, a);
          a = mfma16(qh[ks], kl, a);
        }
        s[ni] = a;
      }
      __builtin_amdgcn_s_setprio(0);

      const bool lastTile = (kt == qt);
      #pragma unroll
      for (int ni = 0; ni < 4; ni++)
        #pragma unroll
        for (int r = 0; r < 4; r++){
          float v = s[ni][r] * SC;
          if (lastTile){
            int kc = kt*64 + ni*16 + la;
            int qr = qbase + w*16 + kg*4 + r;
            if (kc > qr) v = -INFINITY;
          }
          s[ni][r] = v;
        }

      // ---- online softmax (exp2 domain, native v_exp_f32) ----
      float ef[4];
      #pragma unroll
      for (int r = 0; r < 4; r++){
        float v = fmaxf(fmaxf(s[0][r], s[1][r]), fmaxf(s[2][r], s[3][r]));
        for (int o = 1; o < 16; o <<= 1) v = fmaxf(v, __shfl_xor(v, o, 64));
        float mn = fmaxf(m[r], v);
        ef[r] = exp2_fast(m[r] - mn);
        m[r] = mn;
      }
      #pragma unroll
      for (int r = 0; r < 4; r++){
        float rs = 0.f;
        #pragma unroll
        for (int ni = 0; ni < 4; ni++){
          float p = exp2_fast(s[ni][r] - m[r]);
          s[ni][r] = p;
          rs += p;
        }
        for (int o = 1; o < 16; o <<= 1) rs += __shfl_xor(rs, o, 64);
        l[r] = l[r]*ef[r] + rs;
      }
      #pragma unroll
      for (int d = 0; d < 4; d++)
        #pragma unroll
        for (int r = 0; r < 4; r++) Oacc[d][r] *= ef[r];

      // ---- P -> LDS bf16 (wave-private rows), PV from LDS ----
      #pragma unroll
      for (int ni = 0; ni < 4; ni++)
        #pragma unroll
        for (int r = 0; r < 4; r++)
          P[w*16 + kg*4 + r][ni*16 + la] = f2bf_rn(s[ni][r]);

      __builtin_amdgcn_s_setprio(1);
      #pragma unroll
      for (int ks = 0; ks < 2; ks++){
        bf16x8 pa = *(bf16x8*)&P[w*16 + la][ks*32 + kg*8];
        #pragma unroll
        for (int d = 0; d < 4; d++){
          bf16x8 vb = *(bf16x8*)&Vt[d*16 + la][ks*32 + kg*8];
          Oacc[d] = mfma16(pa, vb, Oacc[d]);
        }
      }
      __builtin_amdgcn_s_setprio(0);
    }

    // ---- finalize ----
    #pragma unroll
    for (int d = 0; d < 4; d++)
      #pragma unroll
      for (int r = 0; r < 4; r++){
        float v = Oacc[d][r] / l[r];
        long row = (long)(b*SEQ + qbase + w*16 + kg*4 + r);
        attout[row*DIMN + h*64 + d*16 + la] = f2bf_rn(v);
      }
    __syncthreads();
  }
}

// ---------------- host ----------------
extern "C" void kernel_launch(void* const* d_in, const int* in_sizes, int n_in,
                              void* d_out, int out_size, void* d_ws, size_t ws_size,
                              hipStream_t stream){
  const float* x  = (const float*)d_in[0];
  const float* wq = (const float*)d_in[1];
  const float* wk = (const float*)d_in[2];
  const float* wv = (const float*)d_in[3];
  const float* wo = (const float*)d_in[4];
  float* out = (float*)d_out;
  char* ws = (char*)d_ws;

  const size_t SZ_QD = (size_t)ROWS*DIMN*2;   // 16 MB
  const size_t SZ_KD = (size_t)ROWS*KVD*2;    // 4 MB
  const size_t SZ_WQ = (size_t)DIMN*DIMN*2;   // 8 MB
  const size_t SZ_WK = (size_t)KVD*DIMN*2;    // 2 MB
  const size_t NEED = 65536 + 2*SZ_QD + 2*SZ_WQ + 2*SZ_WK + 2*SZ_QD + 3*SZ_KD;
  if (ws_size < NEED) return;

  float* scales   = (float*)ws;
  float* partials = (float*)(ws + 1024);
  size_t off = 65536;
  auto alloc = [&](size_t bytes)->char*{
    char* p = ws + off; off += (bytes + 255) & ~(size_t)255; return p;
  };
  short* xhi = (short*)alloc(SZ_QD);
  short* xlo = (short*)alloc(SZ_QD);
  short* wqT = (short*)alloc(SZ_WQ);
  short* wkT = (short*)alloc(SZ_WK);
  short* wvT = (short*)alloc(SZ_WK);
  short* woT = (short*)alloc(SZ_WQ);
  short* qhib = (short*)alloc(SZ_QD);
  short* qlob = (short*)alloc(SZ_QD);
  short* khib = (short*)alloc(SZ_KD);
  short* klob = (short*)alloc(SZ_KD);
  short* vTb  = (short*)alloc(SZ_KD);   // V^T: [KVD][ROWS]
  short* atto = xhi;                    // alias: xhi dead after QKVT GEMM

  // 1) thresholds
  {
    dim3 g(256, 4);
    k_abssum4<<<g,256,0,stream>>>(wq, wk, wv, wo, partials);
  }
  k_scales<<<1,256,0,stream>>>(partials, scales);

  // 2) pre-convert operands
  {
    dim3 g(2048, 4);
    k_tern4<<<g,256,0,stream>>>(wq, wk, wv, wo, wqT, wkT, wvT, woT, scales);
  }
  k_prep_x<<<4096,256,0,stream>>>(x, xhi, xlo);

  // 3) Q + K + V^T GEMMs in ONE launch (tail overlap)
  {
    dim3 g(DIMN/128, ROWS/128, 3);
    k_gemm_qkvt<<<g,256,0,stream>>>(xhi, xlo, wqT, wkT, wvT,
                                    qhib, qlob, khib, klob, vTb);
  }

  // 4) attention (balanced pairing, LDS-staged K/V)
  {
    dim3 g(NT/2, NH, BATCH);
    k_attn<<<g,256,0,stream>>>(qhib, qlob, khib, klob, vTb, atto);
  }

  // 5) output GEMM -> f32
  {
    dim3 g(DIMN/128, ROWS/128);
    k_gemm_o<<<g,256,0,stream>>>(atto, woT, out, DIMN, DIMN);
  }
}

// Round 10
// 499.883 us; speedup vs baseline: 1.1184x; 1.1184x over previous
//
#include <hip/hip_runtime.h>
#include <hip/hip_bf16.h>
#include <stdint.h>

#define DIMN 2048
#define KVD  512
#define NH   32
#define BATCH 2
#define SEQ  2048
#define ROWS (BATCH*SEQ)   // 4096
#define NT   (SEQ/64)      // 32 k/q tiles of 64

typedef __attribute__((ext_vector_type(4))) float f32x4;
typedef __attribute__((ext_vector_type(8))) short bf16x8;

__device__ __forceinline__ float bf2f(short s){
  union{uint32_t u;float f;} v; v.u=((uint32_t)(uint16_t)s)<<16; return v.f;
}
__device__ __forceinline__ short f2bf_rn(float f){
  __hip_bfloat16 h = __float2bfloat16(f);   // hardware RNE convert
  short s; __builtin_memcpy(&s, &h, 2); return s;
}
__device__ __forceinline__ f32x4 mfma16(bf16x8 a, bf16x8 b, f32x4 c){
  return __builtin_amdgcn_mfma_f32_16x16x32_bf16(a,b,c,0,0,0);
}
__device__ __forceinline__ short ternbf(float v, float thr){
  return v > thr ? (short)0x3F80 : (v < -thr ? (short)0xBF80 : (short)0);
}
// async global->LDS, 16B per lane; LDS dest = wave-uniform base + lane*16
__device__ __forceinline__ void gload16(const short* g, short* l){
  __builtin_amdgcn_global_load_lds(
      (const __attribute__((address_space(1))) uint32_t*)g,
      (__attribute__((address_space(3))) uint32_t*)l, 16, 0, 0);
}

// ---------------- abs-mean reduction (deterministic, two stage) ----------------
__global__ void k_abssum4(const float* __restrict__ w0, const float* __restrict__ w1,
                          const float* __restrict__ w2, const float* __restrict__ w3,
                          float* __restrict__ partial){
  __shared__ float red[256];
  const float* ptrs[4] = {w0, w1, w2, w3};
  const int ns[4] = {DIMN*DIMN, KVD*DIMN, KVD*DIMN, DIMN*DIMN};
  const int wi = blockIdx.y;
  const float* w = ptrs[wi];
  const int n = ns[wi];
  float s = 0.f;
  for (int i = blockIdx.x*256 + threadIdx.x; i < n; i += 256*gridDim.x) s += fabsf(w[i]);
  red[threadIdx.x] = s; __syncthreads();
  for (int o = 128; o > 0; o >>= 1){
    if (threadIdx.x < o) red[threadIdx.x] += red[threadIdx.x+o];
    __syncthreads();
  }
  if (threadIdx.x == 0) partial[wi*256 + blockIdx.x] = red[0];
}

__global__ void k_scales(const float* __restrict__ partial, float* __restrict__ scales){
  __shared__ float red[256];
  int t = threadIdx.x;
  const int counts[4] = {DIMN*DIMN, KVD*DIMN, KVD*DIMN, DIMN*DIMN};
  for (int wi = 0; wi < 4; wi++){
    red[t] = partial[wi*256 + t]; __syncthreads();
    for (int o = 128; o > 0; o >>= 1){
      if (t < o) red[t] += red[t+o];
      __syncthreads();
    }
    if (t == 0){
      float mean = red[0] / (float)counts[wi];
      scales[wi] = 0.05f * fmaxf(mean, 1e-6f);
    }
    __syncthreads();
  }
}

// ---------------- pre-pass: x -> hi/lo bf16 ----------------
__global__ void k_prep_x(const float* __restrict__ x, short* __restrict__ hi,
                         short* __restrict__ lo){
  long i = ((long)blockIdx.x*256 + threadIdx.x)*8;
  f32x4 a = *(const f32x4*)(x+i);
  f32x4 b = *(const f32x4*)(x+i+4);
  bf16x8 h, l;
  #pragma unroll
  for (int j = 0; j < 4; j++){
    short p = f2bf_rn(a[j]); h[j]   = p; l[j]   = f2bf_rn(a[j]-bf2f(p));
    short q = f2bf_rn(b[j]); h[4+j] = q; l[4+j] = f2bf_rn(b[j]-bf2f(q));
  }
  *(bf16x8*)(hi+i) = h;
  *(bf16x8*)(lo+i) = l;
}

// ---------------- pre-pass: ternarize all 4 weights -> bf16 ----------------
__global__ void k_tern4(const float* __restrict__ w0, const float* __restrict__ w1,
                        const float* __restrict__ w2, const float* __restrict__ w3,
                        short* __restrict__ o0, short* __restrict__ o1,
                        short* __restrict__ o2, short* __restrict__ o3,
                        const float* __restrict__ scales){
  const float* ws[4] = {w0, w1, w2, w3};
  short* os[4] = {o0, o1, o2, o3};
  const int ns[4] = {DIMN*DIMN, KVD*DIMN, KVD*DIMN, DIMN*DIMN};
  const int wi = blockIdx.y;
  long i = ((long)blockIdx.x*256 + threadIdx.x)*8;
  if (i >= ns[wi]) return;
  const float thr = scales[wi];
  const float* w = ws[wi];
  f32x4 a = *(const f32x4*)(w+i);
  f32x4 b = *(const f32x4*)(w+i+4);
  bf16x8 t;
  #pragma unroll
  for (int j = 0; j < 4; j++){
    t[j]   = ternbf(a[j], thr);
    t[4+j] = ternbf(b[j], thr);
  }
  *(bf16x8*)(os[wi]+i) = t;
}

// ------- GEMM core: m97 structure (global_load_lds, linear [128][64] LDS, BK=64) -------
// SPLITA: A=Ahg+Xlg (hi/lo).  SPLITB: B=Bg+Xlg (hi/lo).  OUTF32: f32 output.
template<int SPLITA, int SPLITB, int OUTF32>
__device__ __forceinline__ void gemm_core(
    const short* __restrict__ Ahg, const short* __restrict__ Xlg,
    const short* __restrict__ Bg,
    float* __restrict__ Of, short* __restrict__ Oh, short* __restrict__ Ol,
    bool writelo, int N, int K, int bn, int bm,
    short (*AhS)[64], short (*XlS)[64], short (*BsS)[64]){
  const int tid = threadIdx.x, lane = tid & 63, w = tid >> 6;
  const int wr = w >> 1, wc = w & 1;
  const int la = lane & 15, kg = lane >> 4;
  const int xrb = SPLITA ? bm : bn;   // rows staged into XlS
  f32x4 acc[4][4] = {};
  for (int k0 = 0; k0 < K; k0 += 64){
    #pragma unroll
    for (int j = 0; j < 4; j++){
      const int flat = (w*4 + j)*64 + lane;          // 16B chunk id (lane-varying)
      const int row = flat >> 3, c16 = (flat & 7)*8;
      short* lb = &AhS[0][0] + (w*4 + j)*512;        // wave-uniform LDS base (1KB)
      gload16(Ahg + (long)(bm+row)*K + k0 + c16, lb);
    }
    if constexpr (SPLITA || SPLITB){
      #pragma unroll
      for (int j = 0; j < 4; j++){
        const int flat = (w*4 + j)*64 + lane;
        const int row = flat >> 3, c16 = (flat & 7)*8;
        short* lb = &XlS[0][0] + (w*4 + j)*512;
        gload16(Xlg + (long)(xrb+row)*K + k0 + c16, lb);
      }
    }
    #pragma unroll
    for (int j = 0; j < 4; j++){
      const int flat = (w*4 + j)*64 + lane;
      const int row = flat >> 3, c16 = (flat & 7)*8;
      short* lb = &BsS[0][0] + (w*4 + j)*512;
      gload16(Bg + (long)(bn+row)*K + k0 + c16, lb);
    }
    __syncthreads();   // compiler drains vmcnt before s_barrier
    #pragma unroll
    for (int ks = 0; ks < 2; ks++){
      bf16x8 af[4], bfr[4];
      #pragma unroll
      for (int mi = 0; mi < 4; mi++)
        af[mi] = *(bf16x8*)&AhS[wr*64 + mi*16 + la][ks*32 + kg*8];
      #pragma unroll
      for (int ni = 0; ni < 4; ni++)
        bfr[ni] = *(bf16x8*)&BsS[wc*64 + ni*16 + la][ks*32 + kg*8];
      #pragma unroll
      for (int mi = 0; mi < 4; mi++)
        #pragma unroll
        for (int ni = 0; ni < 4; ni++)
          acc[mi][ni] = mfma16(af[mi], bfr[ni], acc[mi][ni]);
      if constexpr (SPLITA){
        bf16x8 alf[4];
        #pragma unroll
        for (int mi = 0; mi < 4; mi++)
          alf[mi] = *(bf16x8*)&XlS[wr*64 + mi*16 + la][ks*32 + kg*8];
        #pragma unroll
        for (int mi = 0; mi < 4; mi++)
          #pragma unroll
          for (int ni = 0; ni < 4; ni++)
            acc[mi][ni] = mfma16(alf[mi], bfr[ni], acc[mi][ni]);
      }
      if constexpr (SPLITB){
        bf16x8 blf[4];
        #pragma unroll
        for (int ni = 0; ni < 4; ni++)
          blf[ni] = *(bf16x8*)&XlS[wc*64 + ni*16 + la][ks*32 + kg*8];
        #pragma unroll
        for (int mi = 0; mi < 4; mi++)
          #pragma unroll
          for (int ni = 0; ni < 4; ni++)
            acc[mi][ni] = mfma16(af[mi], blf[ni], acc[mi][ni]);
      }
    }
    __syncthreads();
  }
  #pragma unroll
  for (int mi = 0; mi < 4; mi++)
    #pragma unroll
    for (int ni = 0; ni < 4; ni++)
      #pragma unroll
      for (int rr = 0; rr < 4; rr++){
        long row = bm + wr*64 + mi*16 + kg*4 + rr;
        long col = bn + wc*64 + ni*16 + la;
        float v = acc[mi][ni][rr];
        if constexpr (OUTF32){
          Of[row*(long)N + col] = v;
        } else {
          short hb = f2bf_rn(v);
          Oh[row*(long)N + col] = hb;
          if (writelo)
            Ol[row*(long)N + col] = f2bf_rn(v - bf2f(hb));
        }
      }
}

__global__ __launch_bounds__(256) void k_gemm_q(
    const short* __restrict__ Ahg, const short* __restrict__ Alg,
    const short* __restrict__ Bg, short* __restrict__ Oh, short* __restrict__ Ol,
    int N, int K){
  __shared__ short S0[128][64];
  __shared__ short S1[128][64];
  __shared__ short S2[128][64];
  gemm_core<1,0,0>(Ahg, Alg, Bg, nullptr, Oh, Ol, true, N, K,
                   blockIdx.x*128, blockIdx.y*128, S0, S1, S2);
}

// z=0: K GEMM  khi/klo[token][d] = (xhi+xlo) wkT^T
// z=1: V^T GEMM  vT[d][token] = wvT (xhi+xlo)^T  (roles swapped)
__global__ __launch_bounds__(256) void k_gemm_kvt(
    const short* __restrict__ xhi, const short* __restrict__ xlo,
    const short* __restrict__ wkT, const short* __restrict__ wvT,
    short* __restrict__ KOh, short* __restrict__ KOl, short* __restrict__ VT,
    int K){
  __shared__ short S0[128][64];
  __shared__ short S1[128][64];
  __shared__ short S2[128][64];
  if (blockIdx.z == 0){
    gemm_core<1,0,0>(xhi, xlo, wkT, nullptr, KOh, KOl, true, KVD, K,
                     blockIdx.x*128, blockIdx.y*128, S0, S1, S2);
  } else {
    gemm_core<0,1,0>(wvT, xlo, xhi, nullptr, VT, nullptr, false, ROWS, K,
                     blockIdx.y*128, blockIdx.x*128, S0, S1, S2);
  }
}

__global__ __launch_bounds__(256) void k_gemm_o(
    const short* __restrict__ Ahg, const short* __restrict__ Bg,
    float* __restrict__ Of, int N, int K){
  __shared__ short S0[128][64];
  __shared__ short S2[128][64];
  gemm_core<0,0,1>(Ahg, nullptr, Bg, Of, nullptr, nullptr, false, N, K,
                   blockIdx.x*128, blockIdx.y*128, S0, nullptr, S2);
}

// ---------------- GQA causal flash attention ----------------
// Balanced pairing: grid (NT/2=16, head=32, batch=2); block qp does q-tiles {qp, NT-1-qp}
// = exactly 33 k-tiles (uniform). 4 waves x 16 q-rows. K/V^T staged in LDS, pad 68
// (row stride 34 dw -> 0 measured conflicts, r8). Natural-domain softmax w/ __expf
// (r7 measured optimum). 3-MFMA hi/lo split scores.
__global__ __launch_bounds__(256) void k_attn(
    const short* __restrict__ qhi, const short* __restrict__ qlo,
    const short* __restrict__ khi, const short* __restrict__ klo,
    const short* __restrict__ vT, short* __restrict__ attout){
  __shared__ short Kh[64][68];
  __shared__ short Kl[64][68];
  __shared__ short Vt[64][68];
  __shared__ short P[64][68];
  const int qp = blockIdx.x, h = blockIdx.y, b = blockIdx.z;
  const int g = h >> 2;
  const int tid = threadIdx.x, w = tid >> 6, lane = tid & 63;
  const int la = lane & 15, kg = lane >> 4;
  const int trow = tid >> 2, tcol = (tid & 3) * 16;   // staging coords

  for (int phase = 0; phase < 2; phase++){
    const int qt = phase ? (NT - 1 - qp) : qp;
    const int qbase = qt*64;

    bf16x8 qh[2], ql[2];
    {
      long qrow = (long)(b*SEQ + qbase + w*16 + la);
      #pragma unroll
      for (int ks = 0; ks < 2; ks++){
        long off = qrow*DIMN + h*64 + ks*32 + kg*8;
        qh[ks] = *(const bf16x8*)(qhi + off);
        ql[ks] = *(const bf16x8*)(qlo + off);
      }
    }
    f32x4 Oacc[4] = {};
    float m[4], l[4];
    #pragma unroll
    for (int r = 0; r < 4; r++){ m[r] = -INFINITY; l[r] = 0.f; }

    for (int kt = 0; kt <= qt; kt++){
      // ---- cooperative stage: K-hi, K-lo (row=token), V^T (row=d) ----
      __syncthreads();
      {
        const short* ksrc  = khi + (long)(b*SEQ + kt*64 + trow)*KVD + g*64 + tcol;
        const short* klsrc = klo + (long)(b*SEQ + kt*64 + trow)*KVD + g*64 + tcol;
        const short* vsrc  = vT  + (long)(g*64 + trow)*ROWS + b*SEQ + kt*64 + tcol;
        *(bf16x8*)&Kh[trow][tcol]   = *(const bf16x8*)ksrc;
        *(bf16x8*)&Kh[trow][tcol+8] = *(const bf16x8*)(ksrc + 8);
        *(bf16x8*)&Kl[trow][tcol]   = *(const bf16x8*)klsrc;
        *(bf16x8*)&Kl[trow][tcol+8] = *(const bf16x8*)(klsrc + 8);
        *(bf16x8*)&Vt[trow][tcol]   = *(const bf16x8*)vsrc;
        *(bf16x8*)&Vt[trow][tcol+8] = *(const bf16x8*)(vsrc + 8);
      }
      __syncthreads();

      // ---- scores (3-MFMA split) ----
      f32x4 s[4];
      __builtin_amdgcn_s_setprio(1);
      #pragma unroll
      for (int ni = 0; ni < 4; ni++){
        f32x4 a = {0.f,0.f,0.f,0.f};
        #pragma unroll
        for (int ks = 0; ks < 2; ks++){
          bf16x8 kh = *(bf16x8*)&Kh[ni*16 + la][ks*32 + kg*8];
          bf16x8 kl = *(bf16x8*)&Kl[ni*16 + la][ks*32 + kg*8];
          a = mfma16(qh[ks], kh, a);
          a = mfma16(ql[ks], kh, a);
          a = mfma16(qh[ks], kl, a);
        }
        s[ni] = a;
      }
      __builtin_amdgcn_s_setprio(0);

      const bool lastTile = (kt == qt);
      #pragma unroll
      for (int ni = 0; ni < 4; ni++)
        #pragma unroll
        for (int r = 0; r < 4; r++){
          float v = s[ni][r] * 0.125f;
          if (lastTile){
            int kc = kt*64 + ni*16 + la;
            int qr = qbase + w*16 + kg*4 + r;
            if (kc > qr) v = -INFINITY;
          }
          s[ni][r] = v;
        }

      // ---- online softmax (natural domain, fast __expf) ----
      float ef[4];
      #pragma unroll
      for (int r = 0; r < 4; r++){
        float v = fmaxf(fmaxf(s[0][r], s[1][r]), fmaxf(s[2][r], s[3][r]));
        for (int o = 1; o < 16; o <<= 1) v = fmaxf(v, __shfl_xor(v, o, 64));
        float mn = fmaxf(m[r], v);
        ef[r] = __expf(m[r] - mn);
        m[r] = mn;
      }
      #pragma unroll
      for (int r = 0; r < 4; r++){
        float rs = 0.f;
        #pragma unroll
        for (int ni = 0; ni < 4; ni++){
          float p = __expf(s[ni][r] - m[r]);
          s[ni][r] = p;
          rs += p;
        }
        for (int o = 1; o < 16; o <<= 1) rs += __shfl_xor(rs, o, 64);
        l[r] = l[r]*ef[r] + rs;
      }
      #pragma unroll
      for (int d = 0; d < 4; d++)
        #pragma unroll
        for (int r = 0; r < 4; r++) Oacc[d][r] *= ef[r];

      // ---- P -> LDS bf16 (wave-private rows), PV from LDS ----
      #pragma unroll
      for (int ni = 0; ni < 4; ni++)
        #pragma unroll
        for (int r = 0; r < 4; r++)
          P[w*16 + kg*4 + r][ni*16 + la] = f2bf_rn(s[ni][r]);

      __builtin_amdgcn_s_setprio(1);
      #pragma unroll
      for (int ks = 0; ks < 2; ks++){
        bf16x8 pa = *(bf16x8*)&P[w*16 + la][ks*32 + kg*8];
        #pragma unroll
        for (int d = 0; d < 4; d++){
          bf16x8 vb = *(bf16x8*)&Vt[d*16 + la][ks*32 + kg*8];
          Oacc[d] = mfma16(pa, vb, Oacc[d]);
        }
      }
      __builtin_amdgcn_s_setprio(0);
    }

    // ---- finalize ----
    #pragma unroll
    for (int d = 0; d < 4; d++)
      #pragma unroll
      for (int r = 0; r < 4; r++){
        float v = Oacc[d][r] / l[r];
        long row = (long)(b*SEQ + qbase + w*16 + kg*4 + r);
        attout[row*DIMN + h*64 + d*16 + la] = f2bf_rn(v);
      }
    __syncthreads();
  }
}

// ---------------- host ----------------
extern "C" void kernel_launch(void* const* d_in, const int* in_sizes, int n_in,
                              void* d_out, int out_size, void* d_ws, size_t ws_size,
                              hipStream_t stream){
  const float* x  = (const float*)d_in[0];
  const float* wq = (const float*)d_in[1];
  const float* wk = (const float*)d_in[2];
  const float* wv = (const float*)d_in[3];
  const float* wo = (const float*)d_in[4];
  float* out = (float*)d_out;
  char* ws = (char*)d_ws;

  const size_t SZ_QD = (size_t)ROWS*DIMN*2;   // 16 MB
  const size_t SZ_KD = (size_t)ROWS*KVD*2;    // 4 MB
  const size_t SZ_WQ = (size_t)DIMN*DIMN*2;   // 8 MB
  const size_t SZ_WK = (size_t)KVD*DIMN*2;    // 2 MB
  const size_t NEED = 65536 + 2*SZ_QD + 2*SZ_WQ + 2*SZ_WK + 2*SZ_QD + 3*SZ_KD;
  if (ws_size < NEED) return;

  float* scales   = (float*)ws;
  float* partials = (float*)(ws + 1024);
  size_t off = 65536;
  auto alloc = [&](size_t bytes)->char*{
    char* p = ws + off; off += (bytes + 255) & ~(size_t)255; return p;
  };
  short* xhi = (short*)alloc(SZ_QD);
  short* xlo = (short*)alloc(SZ_QD);
  short* wqT = (short*)alloc(SZ_WQ);
  short* wkT = (short*)alloc(SZ_WK);
  short* wvT = (short*)alloc(SZ_WK);
  short* woT = (short*)alloc(SZ_WQ);
  short* qhib = (short*)alloc(SZ_QD);
  short* qlob = (short*)alloc(SZ_QD);
  short* khib = (short*)alloc(SZ_KD);
  short* klob = (short*)alloc(SZ_KD);
  short* vTb  = (short*)alloc(SZ_KD);   // V^T: [KVD][ROWS]
  short* atto = xhi;                    // alias: xhi dead after KVT GEMM

  // 1) thresholds
  {
    dim3 g(256, 4);
    k_abssum4<<<g,256,0,stream>>>(wq, wk, wv, wo, partials);
  }
  k_scales<<<1,256,0,stream>>>(partials, scales);

  // 2) pre-convert operands
  {
    dim3 g(2048, 4);
    k_tern4<<<g,256,0,stream>>>(wq, wk, wv, wo, wqT, wkT, wvT, woT, scales);
  }
  k_prep_x<<<4096,256,0,stream>>>(x, xhi, xlo);

  // 3) Q GEMM, then K + V^T GEMMs (separate launches: sequential = L2 panel reuse)
  {
    dim3 g(DIMN/128, ROWS/128);
    k_gemm_q<<<g,256,0,stream>>>(xhi, xlo, wqT, qhib, qlob, DIMN, DIMN);
  }
  {
    dim3 g(KVD/128, ROWS/128, 2);
    k_gemm_kvt<<<g,256,0,stream>>>(xhi, xlo, wkT, wvT, khib, klob, vTb, DIMN);
  }

  // 4) attention (balanced pairing, LDS-staged K/V)
  {
    dim3 g(NT/2, NH, BATCH);
    k_attn<<<g,256,0,stream>>>(qhib, qlob, khib, klob, vTb, atto);
  }

  // 5) output GEMM -> f32
  {
    dim3 g(DIMN/128, ROWS/128);
    k_gemm_o<<<g,256,0,stream>>>(atto, woT, out, DIMN, DIMN);
  }
}

// Round 11
// 491.349 us; speedup vs baseline: 1.1379x; 1.0174x over previous
//
#include <hip/hip_runtime.h>
#include <hip/hip_bf16.h>
#include <stdint.h>

#define DIMN 2048
#define KVD  512
#define NH   32
#define BATCH 2
#define SEQ  2048
#define ROWS (BATCH*SEQ)   // 4096
#define NT   (SEQ/64)      // 32 k/q tiles of 64

typedef __attribute__((ext_vector_type(4))) float f32x4;
typedef __attribute__((ext_vector_type(8))) short bf16x8;

__device__ __forceinline__ float bf2f(short s){
  union{uint32_t u;float f;} v; v.u=((uint32_t)(uint16_t)s)<<16; return v.f;
}
// manual RNE f32->bf16 (r6-measured attn path; keep byte-identical codegen)
__device__ __forceinline__ short f2bf(float f){
  union{float f;uint32_t u;} v; v.f=f;
  uint32_t r=(v.u + 0x7fffu + ((v.u>>16)&1u))>>16; return (short)r;
}
__device__ __forceinline__ short f2bf_rn(float f){
  __hip_bfloat16 h = __float2bfloat16(f);
  short s; __builtin_memcpy(&s, &h, 2); return s;
}
__device__ __forceinline__ f32x4 mfma16(bf16x8 a, bf16x8 b, f32x4 c){
  return __builtin_amdgcn_mfma_f32_16x16x32_bf16(a,b,c,0,0,0);
}
__device__ __forceinline__ short ternbf(float v, float thr){
  return v > thr ? (short)0x3F80 : (v < -thr ? (short)0xBF80 : (short)0);
}
// async global->LDS, 16B per lane; LDS dest = wave-uniform base + lane*16
__device__ __forceinline__ void gload16(const short* g, short* l){
  __builtin_amdgcn_global_load_lds(
      (const __attribute__((address_space(1))) uint32_t*)g,
      (__attribute__((address_space(3))) uint32_t*)l, 16, 0, 0);
}

// ---------------- abs-mean reduction (deterministic, two stage) ----------------
__global__ void k_abssum4(const float* __restrict__ w0, const float* __restrict__ w1,
                          const float* __restrict__ w2, const float* __restrict__ w3,
                          float* __restrict__ partial){
  __shared__ float red[256];
  const float* ptrs[4] = {w0, w1, w2, w3};
  const int ns[4] = {DIMN*DIMN, KVD*DIMN, KVD*DIMN, DIMN*DIMN};
  const int wi = blockIdx.y;
  const float* w = ptrs[wi];
  const int n = ns[wi];
  float s = 0.f;
  for (int i = blockIdx.x*256 + threadIdx.x; i < n; i += 256*gridDim.x) s += fabsf(w[i]);
  red[threadIdx.x] = s; __syncthreads();
  for (int o = 128; o > 0; o >>= 1){
    if (threadIdx.x < o) red[threadIdx.x] += red[threadIdx.x+o];
    __syncthreads();
  }
  if (threadIdx.x == 0) partial[wi*256 + blockIdx.x] = red[0];
}

__global__ void k_scales(const float* __restrict__ partial, float* __restrict__ scales){
  __shared__ float red[256];
  int t = threadIdx.x;
  const int counts[4] = {DIMN*DIMN, KVD*DIMN, KVD*DIMN, DIMN*DIMN};
  for (int wi = 0; wi < 4; wi++){
    red[t] = partial[wi*256 + t]; __syncthreads();
    for (int o = 128; o > 0; o >>= 1){
      if (t < o) red[t] += red[t+o];
      __syncthreads();
    }
    if (t == 0){
      float mean = red[0] / (float)counts[wi];
      scales[wi] = 0.05f * fmaxf(mean, 1e-6f);
    }
    __syncthreads();
  }
}

// ---------------- pre-pass: x -> hi/lo bf16 ----------------
__global__ void k_prep_x(const float* __restrict__ x, short* __restrict__ hi,
                         short* __restrict__ lo){
  long i = ((long)blockIdx.x*256 + threadIdx.x)*8;
  f32x4 a = *(const f32x4*)(x+i);
  f32x4 b = *(const f32x4*)(x+i+4);
  bf16x8 h, l;
  #pragma unroll
  for (int j = 0; j < 4; j++){
    short p = f2bf(a[j]); h[j]   = p; l[j]   = f2bf(a[j]-bf2f(p));
    short q = f2bf(b[j]); h[4+j] = q; l[4+j] = f2bf(b[j]-bf2f(q));
  }
  *(bf16x8*)(hi+i) = h;
  *(bf16x8*)(lo+i) = l;
}

// ---------------- pre-pass: ternarize all 4 weights -> bf16 ----------------
__global__ void k_tern4(const float* __restrict__ w0, const float* __restrict__ w1,
                        const float* __restrict__ w2, const float* __restrict__ w3,
                        short* __restrict__ o0, short* __restrict__ o1,
                        short* __restrict__ o2, short* __restrict__ o3,
                        const float* __restrict__ scales){
  const float* ws[4] = {w0, w1, w2, w3};
  short* os[4] = {o0, o1, o2, o3};
  const int ns[4] = {DIMN*DIMN, KVD*DIMN, KVD*DIMN, DIMN*DIMN};
  const int wi = blockIdx.y;
  long i = ((long)blockIdx.x*256 + threadIdx.x)*8;
  if (i >= ns[wi]) return;
  const float thr = scales[wi];
  const float* w = ws[wi];
  f32x4 a = *(const f32x4*)(w+i);
  f32x4 b = *(const f32x4*)(w+i+4);
  bf16x8 t;
  #pragma unroll
  for (int j = 0; j < 4; j++){
    t[j]   = ternbf(a[j], thr);
    t[4+j] = ternbf(b[j], thr);
  }
  *(bf16x8*)(os[wi]+i) = t;
}

// ------- GEMM core: m97 structure (global_load_lds, linear [128][64] LDS, BK=64) -------
template<int SPLITA, int SPLITB, int OUTF32>
__device__ __forceinline__ void gemm_core(
    const short* __restrict__ Ahg, const short* __restrict__ Xlg,
    const short* __restrict__ Bg,
    float* __restrict__ Of, short* __restrict__ Oh, short* __restrict__ Ol,
    bool writelo, int N, int K, int bn, int bm,
    short (*AhS)[64], short (*XlS)[64], short (*BsS)[64]){
  const int tid = threadIdx.x, lane = tid & 63, w = tid >> 6;
  const int wr = w >> 1, wc = w & 1;
  const int la = lane & 15, kg = lane >> 4;
  const int xrb = SPLITA ? bm : bn;   // rows staged into XlS
  f32x4 acc[4][4] = {};
  for (int k0 = 0; k0 < K; k0 += 64){
    #pragma unroll
    for (int j = 0; j < 4; j++){
      const int flat = (w*4 + j)*64 + lane;          // 16B chunk id (lane-varying)
      const int row = flat >> 3, c16 = (flat & 7)*8;
      short* lb = &AhS[0][0] + (w*4 + j)*512;        // wave-uniform LDS base (1KB)
      gload16(Ahg + (long)(bm+row)*K + k0 + c16, lb);
    }
    if constexpr (SPLITA || SPLITB){
      #pragma unroll
      for (int j = 0; j < 4; j++){
        const int flat = (w*4 + j)*64 + lane;
        const int row = flat >> 3, c16 = (flat & 7)*8;
        short* lb = &XlS[0][0] + (w*4 + j)*512;
        gload16(Xlg + (long)(xrb+row)*K + k0 + c16, lb);
      }
    }
    #pragma unroll
    for (int j = 0; j < 4; j++){
      const int flat = (w*4 + j)*64 + lane;
      const int row = flat >> 3, c16 = (flat & 7)*8;
      short* lb = &BsS[0][0] + (w*4 + j)*512;
      gload16(Bg + (long)(bn+row)*K + k0 + c16, lb);
    }
    __syncthreads();   // compiler drains vmcnt before s_barrier
    #pragma unroll
    for (int ks = 0; ks < 2; ks++){
      bf16x8 af[4], bfr[4];
      #pragma unroll
      for (int mi = 0; mi < 4; mi++)
        af[mi] = *(bf16x8*)&AhS[wr*64 + mi*16 + la][ks*32 + kg*8];
      #pragma unroll
      for (int ni = 0; ni < 4; ni++)
        bfr[ni] = *(bf16x8*)&BsS[wc*64 + ni*16 + la][ks*32 + kg*8];
      #pragma unroll
      for (int mi = 0; mi < 4; mi++)
        #pragma unroll
        for (int ni = 0; ni < 4; ni++)
          acc[mi][ni] = mfma16(af[mi], bfr[ni], acc[mi][ni]);
      if constexpr (SPLITA){
        bf16x8 alf[4];
        #pragma unroll
        for (int mi = 0; mi < 4; mi++)
          alf[mi] = *(bf16x8*)&XlS[wr*64 + mi*16 + la][ks*32 + kg*8];
        #pragma unroll
        for (int mi = 0; mi < 4; mi++)
          #pragma unroll
          for (int ni = 0; ni < 4; ni++)
            acc[mi][ni] = mfma16(alf[mi], bfr[ni], acc[mi][ni]);
      }
      if constexpr (SPLITB){
        bf16x8 blf[4];
        #pragma unroll
        for (int ni = 0; ni < 4; ni++)
          blf[ni] = *(bf16x8*)&XlS[wc*64 + ni*16 + la][ks*32 + kg*8];
        #pragma unroll
        for (int mi = 0; mi < 4; mi++)
          #pragma unroll
          for (int ni = 0; ni < 4; ni++)
            acc[mi][ni] = mfma16(af[mi], blf[ni], acc[mi][ni]);
      }
    }
    __syncthreads();
  }
  #pragma unroll
  for (int mi = 0; mi < 4; mi++)
    #pragma unroll
    for (int ni = 0; ni < 4; ni++)
      #pragma unroll
      for (int rr = 0; rr < 4; rr++){
        long row = bm + wr*64 + mi*16 + kg*4 + rr;
        long col = bn + wc*64 + ni*16 + la;
        float v = acc[mi][ni][rr];
        if constexpr (OUTF32){
          Of[row*(long)N + col] = v;
        } else {
          short hb = f2bf_rn(v);
          Oh[row*(long)N + col] = hb;
          if (writelo)
            Ol[row*(long)N + col] = f2bf_rn(v - bf2f(hb));
        }
      }
}

__global__ __launch_bounds__(256) void k_gemm_q(
    const short* __restrict__ Ahg, const short* __restrict__ Alg,
    const short* __restrict__ Bg, short* __restrict__ Oh, short* __restrict__ Ol,
    int N, int K){
  __shared__ short S0[128][64];
  __shared__ short S1[128][64];
  __shared__ short S2[128][64];
  gemm_core<1,0,0>(Ahg, Alg, Bg, nullptr, Oh, Ol, true, N, K,
                   blockIdx.x*128, blockIdx.y*128, S0, S1, S2);
}

// z=0: K GEMM  khi/klo[token][d] = (xhi+xlo) wkT^T   (split A)
// z=1: V^T GEMM  vT[d][token] = wvT xhi^T            (no split: bf16-out rounding dominates)
__global__ __launch_bounds__(256) void k_gemm_kvt(
    const short* __restrict__ xhi, const short* __restrict__ xlo,
    const short* __restrict__ wkT, const short* __restrict__ wvT,
    short* __restrict__ KOh, short* __restrict__ KOl, short* __restrict__ VT,
    int K){
  __shared__ short S0[128][64];
  __shared__ short S1[128][64];
  __shared__ short S2[128][64];
  if (blockIdx.z == 0){
    gemm_core<1,0,0>(xhi, xlo, wkT, nullptr, KOh, KOl, true, KVD, K,
                     blockIdx.x*128, blockIdx.y*128, S0, S1, S2);
  } else {
    gemm_core<0,0,0>(wvT, nullptr, xhi, nullptr, VT, nullptr, false, ROWS, K,
                     blockIdx.y*128, blockIdx.x*128, S0, S1, S2);
  }
}

__global__ __launch_bounds__(256) void k_gemm_o(
    const short* __restrict__ Ahg, const short* __restrict__ Bg,
    float* __restrict__ Of, int N, int K){
  __shared__ short S0[128][64];
  __shared__ short S2[128][64];
  gemm_core<0,0,1>(Ahg, nullptr, Bg, Of, nullptr, nullptr, false, N, K,
                   blockIdx.x*128, blockIdx.y*128, S0, nullptr, S2);
}

// ---------------- GQA causal flash attention ----------------
// r6-measured structure (162 us): pairing, pad-72, manual f2bf, __expf, setprio.
// + T14 async-STAGE split: next tile's K/V loads issue into REGISTERS right after
// the post-write barrier, hiding L2 latency under the current tile's compute;
// regs are written to LDS at the top of the next iteration (vmcnt drained there).
__global__ __launch_bounds__(256) void k_attn(
    const short* __restrict__ qhi, const short* __restrict__ qlo,
    const short* __restrict__ khi, const short* __restrict__ klo,
    const short* __restrict__ vT, short* __restrict__ attout){
  __shared__ short Kh[64][72];
  __shared__ short Kl[64][72];
  __shared__ short Vt[64][72];
  __shared__ short P[64][72];
  const int qp = blockIdx.x, h = blockIdx.y, b = blockIdx.z;
  const int g = h >> 2;
  const int tid = threadIdx.x, w = tid >> 6, lane = tid & 63;
  const int la = lane & 15, kg = lane >> 4;
  const int trow = tid >> 2, tcol = (tid & 3) * 16;   // staging coords

  for (int phase = 0; phase < 2; phase++){
    const int qt = phase ? (NT - 1 - qp) : qp;
    const int qbase = qt*64;

    bf16x8 qh[2], ql[2];
    {
      long qrow = (long)(b*SEQ + qbase + w*16 + la);
      #pragma unroll
      for (int ks = 0; ks < 2; ks++){
        long off = qrow*DIMN + h*64 + ks*32 + kg*8;
        qh[ks] = *(const bf16x8*)(qhi + off);
        ql[ks] = *(const bf16x8*)(qlo + off);
      }
    }
    f32x4 Oacc[4] = {};
    float m[4], l[4];
    #pragma unroll
    for (int r = 0; r < 4; r++){ m[r] = -INFINITY; l[r] = 0.f; }

    // prefetch registers for tile kt (written to LDS at loop top)
    bf16x8 rkh0, rkh1, rkl0, rkl1, rvt0, rvt1;
    {
      const short* ksrc  = khi + (long)(b*SEQ + trow)*KVD + g*64 + tcol;
      const short* klsrc = klo + (long)(b*SEQ + trow)*KVD + g*64 + tcol;
      const short* vsrc  = vT  + (long)(g*64 + trow)*ROWS + b*SEQ + tcol;
      rkh0 = *(const bf16x8*)ksrc;    rkh1 = *(const bf16x8*)(ksrc + 8);
      rkl0 = *(const bf16x8*)klsrc;   rkl1 = *(const bf16x8*)(klsrc + 8);
      rvt0 = *(const bf16x8*)vsrc;    rvt1 = *(const bf16x8*)(vsrc + 8);
    }

    for (int kt = 0; kt <= qt; kt++){
      __syncthreads();   // previous tile's LDS reads complete
      *(bf16x8*)&Kh[trow][tcol]   = rkh0;
      *(bf16x8*)&Kh[trow][tcol+8] = rkh1;
      *(bf16x8*)&Kl[trow][tcol]   = rkl0;
      *(bf16x8*)&Kl[trow][tcol+8] = rkl1;
      *(bf16x8*)&Vt[trow][tcol]   = rvt0;
      *(bf16x8*)&Vt[trow][tcol+8] = rvt1;
      __syncthreads();   // writes visible

      // issue next tile's loads NOW — latency hides under compute below
      {
        const int ktn = (kt < qt) ? (kt + 1) : qt;   // clamp: no OOB on last tile
        const short* ksrc  = khi + (long)(b*SEQ + ktn*64 + trow)*KVD + g*64 + tcol;
        const short* klsrc = klo + (long)(b*SEQ + ktn*64 + trow)*KVD + g*64 + tcol;
        const short* vsrc  = vT  + (long)(g*64 + trow)*ROWS + b*SEQ + ktn*64 + tcol;
        rkh0 = *(const bf16x8*)ksrc;    rkh1 = *(const bf16x8*)(ksrc + 8);
        rkl0 = *(const bf16x8*)klsrc;   rkl1 = *(const bf16x8*)(klsrc + 8);
        rvt0 = *(const bf16x8*)vsrc;    rvt1 = *(const bf16x8*)(vsrc + 8);
      }

      // ---- scores (3-MFMA split) ----
      f32x4 s[4];
      __builtin_amdgcn_s_setprio(1);
      #pragma unroll
      for (int ni = 0; ni < 4; ni++){
        f32x4 a = {0.f,0.f,0.f,0.f};
        #pragma unroll
        for (int ks = 0; ks < 2; ks++){
          bf16x8 kh = *(bf16x8*)&Kh[ni*16 + la][ks*32 + kg*8];
          bf16x8 kl = *(bf16x8*)&Kl[ni*16 + la][ks*32 + kg*8];
          a = mfma16(qh[ks], kh, a);
          a = mfma16(ql[ks], kh, a);
          a = mfma16(qh[ks], kl, a);
        }
        s[ni] = a;
      }
      __builtin_amdgcn_s_setprio(0);

      const bool lastTile = (kt == qt);
      #pragma unroll
      for (int ni = 0; ni < 4; ni++)
        #pragma unroll
        for (int r = 0; r < 4; r++){
          float v = s[ni][r] * 0.125f;
          if (lastTile){
            int kc = kt*64 + ni*16 + la;
            int qr = qbase + w*16 + kg*4 + r;
            if (kc > qr) v = -INFINITY;
          }
          s[ni][r] = v;
        }

      // ---- online softmax (natural domain, fast __expf) ----
      float ef[4];
      #pragma unroll
      for (int r = 0; r < 4; r++){
        float v = fmaxf(fmaxf(s[0][r], s[1][r]), fmaxf(s[2][r], s[3][r]));
        for (int o = 1; o < 16; o <<= 1) v = fmaxf(v, __shfl_xor(v, o, 64));
        float mn = fmaxf(m[r], v);
        ef[r] = __expf(m[r] - mn);
        m[r] = mn;
      }
      #pragma unroll
      for (int r = 0; r < 4; r++){
        float rs = 0.f;
        #pragma unroll
        for (int ni = 0; ni < 4; ni++){
          float p = __expf(s[ni][r] - m[r]);
          s[ni][r] = p;
          rs += p;
        }
        for (int o = 1; o < 16; o <<= 1) rs += __shfl_xor(rs, o, 64);
        l[r] = l[r]*ef[r] + rs;
      }
      #pragma unroll
      for (int d = 0; d < 4; d++)
        #pragma unroll
        for (int r = 0; r < 4; r++) Oacc[d][r] *= ef[r];

      // ---- P -> LDS bf16 (wave-private rows), PV from LDS ----
      #pragma unroll
      for (int ni = 0; ni < 4; ni++)
        #pragma unroll
        for (int r = 0; r < 4; r++)
          P[w*16 + kg*4 + r][ni*16 + la] = f2bf(s[ni][r]);

      __builtin_amdgcn_s_setprio(1);
      #pragma unroll
      for (int ks = 0; ks < 2; ks++){
        bf16x8 pa = *(bf16x8*)&P[w*16 + la][ks*32 + kg*8];
        #pragma unroll
        for (int d = 0; d < 4; d++){
          bf16x8 vb = *(bf16x8*)&Vt[d*16 + la][ks*32 + kg*8];
          Oacc[d] = mfma16(pa, vb, Oacc[d]);
        }
      }
      __builtin_amdgcn_s_setprio(0);
    }

    // ---- finalize ----
    #pragma unroll
    for (int d = 0; d < 4; d++)
      #pragma unroll
      for (int r = 0; r < 4; r++){
        float v = Oacc[d][r] / l[r];
        long row = (long)(b*SEQ + qbase + w*16 + kg*4 + r);
        attout[row*DIMN + h*64 + d*16 + la] = f2bf(v);
      }
    __syncthreads();
  }
}

// ---------------- host ----------------
extern "C" void kernel_launch(void* const* d_in, const int* in_sizes, int n_in,
                              void* d_out, int out_size, void* d_ws, size_t ws_size,
                              hipStream_t stream){
  const float* x  = (const float*)d_in[0];
  const float* wq = (const float*)d_in[1];
  const float* wk = (const float*)d_in[2];
  const float* wv = (const float*)d_in[3];
  const float* wo = (const float*)d_in[4];
  float* out = (float*)d_out;
  char* ws = (char*)d_ws;

  const size_t SZ_QD = (size_t)ROWS*DIMN*2;   // 16 MB
  const size_t SZ_KD = (size_t)ROWS*KVD*2;    // 4 MB
  const size_t SZ_WQ = (size_t)DIMN*DIMN*2;   // 8 MB
  const size_t SZ_WK = (size_t)KVD*DIMN*2;    // 2 MB
  const size_t NEED = 65536 + 2*SZ_QD + 2*SZ_WQ + 2*SZ_WK + 2*SZ_QD + 3*SZ_KD;
  if (ws_size < NEED) return;

  float* scales   = (float*)ws;
  float* partials = (float*)(ws + 1024);
  size_t off = 65536;
  auto alloc = [&](size_t bytes)->char*{
    char* p = ws + off; off += (bytes + 255) & ~(size_t)255; return p;
  };
  short* xhi = (short*)alloc(SZ_QD);
  short* xlo = (short*)alloc(SZ_QD);
  short* wqT = (short*)alloc(SZ_WQ);
  short* wkT = (short*)alloc(SZ_WK);
  short* wvT = (short*)alloc(SZ_WK);
  short* woT = (short*)alloc(SZ_WQ);
  short* qhib = (short*)alloc(SZ_QD);
  short* qlob = (short*)alloc(SZ_QD);
  short* khib = (short*)alloc(SZ_KD);
  short* klob = (short*)alloc(SZ_KD);
  short* vTb  = (short*)alloc(SZ_KD);   // V^T: [KVD][ROWS]
  short* atto = xhi;                    // alias: xhi dead after KVT GEMM

  // 1) thresholds
  {
    dim3 g(256, 4);
    k_abssum4<<<g,256,0,stream>>>(wq, wk, wv, wo, partials);
  }
  k_scales<<<1,256,0,stream>>>(partials, scales);

  // 2) pre-convert operands
  {
    dim3 g(2048, 4);
    k_tern4<<<g,256,0,stream>>>(wq, wk, wv, wo, wqT, wkT, wvT, woT, scales);
  }
  k_prep_x<<<4096,256,0,stream>>>(x, xhi, xlo);

  // 3) Q GEMM, then K + V^T GEMMs (separate launches: sequential = L2 panel reuse)
  {
    dim3 g(DIMN/128, ROWS/128);
    k_gemm_q<<<g,256,0,stream>>>(xhi, xlo, wqT, qhib, qlob, DIMN, DIMN);
  }
  {
    dim3 g(KVD/128, ROWS/128, 2);
    k_gemm_kvt<<<g,256,0,stream>>>(xhi, xlo, wkT, wvT, khib, klob, vTb, DIMN);
  }

  // 4) attention (balanced pairing, LDS-staged K/V, async-STAGE prefetch)
  {
    dim3 g(NT/2, NH, BATCH);
    k_attn<<<g,256,0,stream>>>(qhib, qlob, khib, klob, vTb, atto);
  }

  // 5) output GEMM -> f32
  {
    dim3 g(DIMN/128, ROWS/128);
    k_gemm_o<<<g,256,0,stream>>>(atto, woT, out, DIMN, DIMN);
  }
}